// Round 5
// baseline (2589.033 us; speedup 1.0000x reference)
//
#include <hip/hip_runtime.h>

#define NB 32
#define NLEN 128
#define NS 96
#define NE 768
#define NH 300
#define NR 41
#define RCH 5     // r-chunks {9,8,8,8,8} -> grid 800 ~= 768 concurrent capacity
#define OCT 5     // o-tiles of 64

// workspace offsets (in floats)
#define OFF_TSUM   0u
#define OFF_ELEN   24576u
#define OFF_RLEN   24608u
#define OFF_HCM    24640u
#define OFF_TAB    34240u
#define OFF_HGA    49240u
#define OFF_HGB    970840u
#define OFF_SWT    1892440u
#define OFF_U      1904740u
#define OFF_SPRE   2030692u
#define OFF_RDEN   2156644u
#define OFF_C      2282596u
#define OFF_P      2408548u   // [RCH][NB][NS][NH] f32 = 4,608,000 floats

// swizzle: spread 32-float groups by 4; quads/8-runs stay contiguous.
__device__ __forceinline__ int SW(int o) { return o + ((o >> 5) << 2); }

__device__ __forceinline__ float wave_reduce(float v) {
#pragma unroll
  for (int off = 32; off > 0; off >>= 1) v += __shfl_down(v, off);
  return v;
}

// ---- tsum[b,e] = sum_l text[b,l,e] ----
__global__ void k_tsum(const float* __restrict__ text, float* __restrict__ tsum) {
  int b = blockIdx.x;
  int tid = threadIdx.x;
  for (int e = tid; e < NE; e += 256) {
    const float* p = text + (size_t)b * NLEN * NE + e;
    float s = 0.f;
#pragma unroll 4
    for (int l = 0; l < NLEN; ++l) s += p[(size_t)l * NE];
    tsum[b * NE + e] = s;
  }
}

// ---- lengths ----
__global__ void k_len(const int* __restrict__ cm, const int* __restrict__ pt,
                      float* __restrict__ elen, float* __restrict__ rlen) {
  int b = threadIdx.x;
  if (b < NB) {
    int s1 = 0;
    for (int l = 0; l < NLEN; ++l) s1 += cm[b * NLEN + l];
    int s2 = 0;
    for (int s = 0; s < NS; ++s) s2 += (pt[b * NS + s] != 0) ? 1 : 0;
    elen[b] = (float)s1;
    rlen[b] = (float)s2;
  }
}

// ---- hc_mean[b,h] = (tsum[b]·linW[:,h] + L*linb[h]) / elen[b] ----
__global__ void k_hcmean(const float* __restrict__ tsum, const float* __restrict__ linW,
                         const float* __restrict__ linb, const float* __restrict__ elen,
                         float* __restrict__ hcm) {
  int idx = blockIdx.x * 256 + threadIdx.x;
  if (idx >= NB * NH) return;
  int b = idx / NH, h = idx - b * NH;
  const float* tp = tsum + b * NE;
  float s = 0.f;
  for (int e = 0; e < NE; ++e) s += tp[e] * linW[(size_t)e * NH + h];
  hcm[idx] = (s + (float)NLEN * linb[h]) / elen[b];
}

// ---- table[p,h] = pos_emb[p]·linW[:,h] + linb[h] ----
__global__ void k_table(const float* __restrict__ pemb, const float* __restrict__ linW,
                        const float* __restrict__ linb, float* __restrict__ tab) {
  int idx = blockIdx.x * 256 + threadIdx.x;
  if (idx >= 50 * NH) return;
  int p = idx / NH, h = idx - p * NH;
  const float* pp = pemb + (size_t)p * NE;
  float s = 0.f;
  for (int e = 0; e < NE; ++e) s += pp[e] * linW[(size_t)e * NH + h];
  tab[idx] = s + linb[h];
}

// ---- hg0[b,s,h] = table[pt[b,s],h] ----
__global__ void k_gather(const int* __restrict__ pt, const float* __restrict__ tab,
                         float* __restrict__ hg) {
  int idx = blockIdx.x * 256 + threadIdx.x;
  if (idx >= NB * NS * NH) return;
  int h = idx % NH;
  int bs = idx / NH;
  hg[idx] = tab[pt[bs] * NH + h];
}

// ---- swt[r,i] = sum_o W[r,i,o]*sw[o] ----
__global__ void k_swt(const float* __restrict__ Wl, const float* __restrict__ sw,
                      float* __restrict__ swt) {
  int gw = (blockIdx.x * blockDim.x + threadIdx.x) >> 6;
  int lane = threadIdx.x & 63;
  if (gw >= NR * NH) return;
  const float* wp = Wl + (size_t)gw * NH;
  float s = 0.f;
  for (int o = lane; o < NH; o += 64) s += wp[o] * sw[o];
  s = wave_reduce(s);
  if (lane == 0) swt[gw] = s;
}

// ---- u[b,r,t] = x[b,t,:]·swt[r,:] ----
__global__ void k_u(const float* __restrict__ x, const float* __restrict__ swt,
                    float* __restrict__ u) {
  int gw = (blockIdx.x * blockDim.x + threadIdx.x) >> 6;
  int lane = threadIdx.x & 63;
  if (gw >= NB * NR * NS) return;
  int t = gw % NS;
  int br = gw / NS;
  int r = br % NR;
  int b = br / NR;
  const float* xp = x + (size_t)(b * NS + t) * NH;
  const float* sp = swt + (size_t)r * NH;
  float s = 0.f;
  for (int i = lane; i < NH; i += 64) s += xp[i] * sp[i];
  s = wave_reduce(s);
  if (lane == 0) u[gw] = s;
}

// ---- denom + v + pre-softmax scores ----
__global__ void k_scores(const float* __restrict__ adj, const float* __restrict__ u,
                         const float* __restrict__ sb, float* __restrict__ spre,
                         float* __restrict__ rden) {
  int gw = (blockIdx.x * blockDim.x + threadIdx.x) >> 6;
  int lane = threadIdx.x & 63;
  if (gw >= NB * NR * NS) return;
  int s = gw % NS;
  int br = gw / NS;
  int r = br % NR;
  int b = br / NR;
  const float* ap = adj + (size_t)gw * NS;
  const float* up = u + (size_t)br * NS;
  float d = 0.f, v = 0.f;
  for (int t = lane; t < NS; t += 64) {
    float a = ap[t];
    d += a;
    v += a * up[t];
  }
  d = wave_reduce(d);
  v = wave_reduce(v);
  if (lane == 0) {
    float ds = (d == 0.f) ? 1.f : d;
    int o = (b * NS + s) * NR + r;
    spre[o] = v / ds + sb[0];
    rden[o] = 1.f / ds;
  }
}

// ---- softmax over r, fold 1/denom: c[b,r,s] ----
__global__ void k_softmax(const float* __restrict__ spre, const float* __restrict__ rden,
                          float* __restrict__ c) {
  int bs = blockIdx.x * 256 + threadIdx.x;
  if (bs >= NB * NS) return;
  int b = bs / NS, s = bs - b * NS;
  float vals[NR];
  float m = -1e30f;
#pragma unroll
  for (int r = 0; r < NR; ++r) {
    vals[r] = spre[(size_t)bs * NR + r];
    m = fmaxf(m, vals[r]);
  }
  float sum = 0.f;
#pragma unroll
  for (int r = 0; r < NR; ++r) {
    float e = expf(vals[r] - m);
    vals[r] = e;
    sum += e;
  }
  float inv = 1.f / sum;
#pragma unroll
  for (int r = 0; r < NR; ++r) {
    c[((size_t)(b * NR + r)) * NS + s] = vals[r] * inv * rden[(size_t)bs * NR + r];
  }
}

// ---- fused per-relation: Ht = x[b]@W_r[:,o-tile]; accO += (c⊙adjT)@Ht ----
// block = (b, rg, oc); 192 threads; micro-tile 4x8.
// Register-prefetch pipeline: barrier / ds_write(s) + issue loads(s+1) / barrier / compute(s)
__global__ __launch_bounds__(192)
void k_fused(const float* __restrict__ adj, const float* __restrict__ x,
             const float* __restrict__ cbuf, const float* __restrict__ Wl,
             float* __restrict__ P) {
  __shared__ __align__(16) float sA[32 * 108];  // x-chunk / scaled-adjT chunk, [k][SW(row)]
  __shared__ __align__(16) float sB[32 * 68];   // W-chunk, [k][SW(o)]
  __shared__ __align__(16) float sH[96 * 68];   // Ht, [t][SW(o)]

  const int tid = threadIdx.x;
  // XCD-chunked bijective swizzle: 800 = 8 * 100 exactly
  int w = ((blockIdx.x & 7) * 100) + (blockIdx.x >> 3);
  const int oc = w % 5; w /= 5;
  const int rg = w % 5;
  const int b = w / 5;
  const int o0 = oc * 64;
  const int r0 = (rg == 0) ? 0 : (9 + (rg - 1) * 8);
  const int nr = (rg == 0) ? 9 : 8;

  // per-thread staging constants (192 | 8 and 192 | 16 -> closed forms)
  const int arow = tid >> 3;          // +24 per slot p (rows 0..95)
  const int akq  = (tid & 7) * 4;     // k-quad within chunk
  const int wo4  = (tid & 15) * 4;    // o-quad
  const int wk   = tid >> 4;          // +12 per slot p (k rows 0..35)
  const int wsw  = SW(wo4);
  const bool wv2 = (tid < 128);
  const bool wov = (o0 + wo4 + 4 <= NH);   // full-quad validity in o

  const int g1 = tid >> 3;        // row-group (t in G1, s in G2)
  const int g2 = tid & 7;         // col-group
  const int fa = SW(g1 * 4);
  const int fb = SW(g2 * 8);

  const float* xb = x + (size_t)b * NS * NH;

  float accO[4][8];
#pragma unroll
  for (int i = 0; i < 4; ++i)
#pragma unroll
    for (int j = 0; j < 8; ++j) accO[i][j] = 0.f;
  float acc1[4][8];

  // stage registers
  float4 pa0, pa1, pa2, pa3;
  float4 pw0, pw1, pw2;
  float pc0, pc1, pc2, pc3;

  const float4 fz = make_float4(0.f, 0.f, 0.f, 0.f);

  // ---- issue stage (rr, it): it<10 -> G1 chunk it (x+W); else G2 chunk it-10 (adj+c)
#define ISSUE(RR, IT)                                                          \
  do {                                                                         \
    const int r_ = r0 + (RR);                                                  \
    if ((IT) < 10) {                                                           \
      const int k0_ = (IT) * 32;                                               \
      const int kx_ = k0_ + akq;                                               \
      if (kx_ + 4 <= NH) {                                                     \
        pa0 = *(const float4*)&xb[(arow +  0) * NH + kx_];                     \
        pa1 = *(const float4*)&xb[(arow + 24) * NH + kx_];                     \
        pa2 = *(const float4*)&xb[(arow + 48) * NH + kx_];                     \
        pa3 = *(const float4*)&xb[(arow + 72) * NH + kx_];                     \
      } else { pa0 = fz; pa1 = fz; pa2 = fz; pa3 = fz; }                       \
      const float* wp_ = Wl + (size_t)r_ * NH * NH;                            \
      const int ow_ = o0 + wo4;                                                \
      const int kw0_ = k0_ + wk;                                               \
      pw0 = (wov && kw0_ < NH) ? *(const float4*)&wp_[(size_t)kw0_ * NH + ow_] : fz; \
      const int kw1_ = kw0_ + 12;                                              \
      pw1 = (wov && kw1_ < NH) ? *(const float4*)&wp_[(size_t)kw1_ * NH + ow_] : fz; \
      const int kw2_ = kw0_ + 24;                                              \
      pw2 = (wv2 && wov && kw2_ < NH) ? *(const float4*)&wp_[(size_t)kw2_ * NH + ow_] : fz; \
    } else {                                                                   \
      const int t0_ = ((IT) - 10) * 32;                                        \
      const float* ap_ = adj + (size_t)(b * NR + r_) * NS * NS;                \
      const float* cp_ = cbuf + (size_t)(b * NR + r_) * NS;                    \
      pa0 = *(const float4*)&ap_[(arow +  0) * NS + t0_ + akq];                \
      pa1 = *(const float4*)&ap_[(arow + 24) * NS + t0_ + akq];                \
      pa2 = *(const float4*)&ap_[(arow + 48) * NS + t0_ + akq];                \
      pa3 = *(const float4*)&ap_[(arow + 72) * NS + t0_ + akq];                \
      pc0 = cp_[arow]; pc1 = cp_[arow + 24];                                   \
      pc2 = cp_[arow + 48]; pc3 = cp_[arow + 72];                              \
    }                                                                          \
  } while (0)

  ISSUE(0, 0);

  int rr = 0, it = 0;
  const int tot = nr * 13;
  for (int s = 0; s < tot; ++s) {
    __syncthreads();   // previous compute done; LDS free to overwrite

    if (it == 10) {
      // publish Ht (acc1 complete after G1 chunk 9)
#pragma unroll
      for (int i = 0; i < 4; ++i) {
        *(float4*)&sH[(g1 * 4 + i) * 68 + fb] =
            make_float4(acc1[i][0], acc1[i][1], acc1[i][2], acc1[i][3]);
        *(float4*)&sH[(g1 * 4 + i) * 68 + fb + 4] =
            make_float4(acc1[i][4], acc1[i][5], acc1[i][6], acc1[i][7]);
      }
    }

    // ---- write stage s to LDS
    if (it < 10) {
      const int c0 = SW(arow), c1 = SW(arow + 24), c2 = SW(arow + 48), c3 = SW(arow + 72);
      sA[(akq + 0) * 108 + c0] = pa0.x; sA[(akq + 1) * 108 + c0] = pa0.y;
      sA[(akq + 2) * 108 + c0] = pa0.z; sA[(akq + 3) * 108 + c0] = pa0.w;
      sA[(akq + 0) * 108 + c1] = pa1.x; sA[(akq + 1) * 108 + c1] = pa1.y;
      sA[(akq + 2) * 108 + c1] = pa1.z; sA[(akq + 3) * 108 + c1] = pa1.w;
      sA[(akq + 0) * 108 + c2] = pa2.x; sA[(akq + 1) * 108 + c2] = pa2.y;
      sA[(akq + 2) * 108 + c2] = pa2.z; sA[(akq + 3) * 108 + c2] = pa2.w;
      sA[(akq + 0) * 108 + c3] = pa3.x; sA[(akq + 1) * 108 + c3] = pa3.y;
      sA[(akq + 2) * 108 + c3] = pa3.z; sA[(akq + 3) * 108 + c3] = pa3.w;
      *(float4*)&sB[(wk + 0) * 68 + wsw] = pw0;
      *(float4*)&sB[(wk + 12) * 68 + wsw] = pw1;
      if (wv2) *(float4*)&sB[(wk + 24) * 68 + wsw] = pw2;
    } else {
      const int c0 = SW(arow), c1 = SW(arow + 24), c2 = SW(arow + 48), c3 = SW(arow + 72);
      sA[(akq + 0) * 108 + c0] = pa0.x * pc0; sA[(akq + 1) * 108 + c0] = pa0.y * pc0;
      sA[(akq + 2) * 108 + c0] = pa0.z * pc0; sA[(akq + 3) * 108 + c0] = pa0.w * pc0;
      sA[(akq + 0) * 108 + c1] = pa1.x * pc1; sA[(akq + 1) * 108 + c1] = pa1.y * pc1;
      sA[(akq + 2) * 108 + c1] = pa1.z * pc1; sA[(akq + 3) * 108 + c1] = pa1.w * pc1;
      sA[(akq + 0) * 108 + c2] = pa2.x * pc2; sA[(akq + 1) * 108 + c2] = pa2.y * pc2;
      sA[(akq + 2) * 108 + c2] = pa2.z * pc2; sA[(akq + 3) * 108 + c2] = pa2.w * pc2;
      sA[(akq + 0) * 108 + c3] = pa3.x * pc3; sA[(akq + 1) * 108 + c3] = pa3.y * pc3;
      sA[(akq + 2) * 108 + c3] = pa3.z * pc3; sA[(akq + 3) * 108 + c3] = pa3.w * pc3;
    }

    // ---- issue loads for stage s+1 (latency hides under compute below)
    if (s + 1 < tot) {
      int it2 = it + 1, rr2 = rr;
      if (it2 == 13) { it2 = 0; ++rr2; }
      ISSUE(rr2, it2);
    }

    __syncthreads();   // staged data visible

    // ---- compute stage s
    if (it < 10) {
      if (it == 0) {
#pragma unroll
        for (int i = 0; i < 4; ++i)
#pragma unroll
          for (int j = 0; j < 8; ++j) acc1[i][j] = 0.f;
      }
#pragma unroll
      for (int kk = 0; kk < 32; ++kk) {
        float4 a = *(const float4*)&sA[kk * 108 + fa];
        float4 b0 = *(const float4*)&sB[kk * 68 + fb];
        float4 b1 = *(const float4*)&sB[kk * 68 + fb + 4];
        float as[4] = {a.x, a.y, a.z, a.w};
        float bs[8] = {b0.x, b0.y, b0.z, b0.w, b1.x, b1.y, b1.z, b1.w};
#pragma unroll
        for (int i = 0; i < 4; ++i)
#pragma unroll
          for (int j = 0; j < 8; ++j) acc1[i][j] += as[i] * bs[j];
      }
    } else {
      const int t0 = (it - 10) * 32;
#pragma unroll
      for (int kk = 0; kk < 32; ++kk) {
        float4 a = *(const float4*)&sA[kk * 108 + fa];
        float4 b0 = *(const float4*)&sH[(t0 + kk) * 68 + fb];
        float4 b1 = *(const float4*)&sH[(t0 + kk) * 68 + fb + 4];
        float as[4] = {a.x, a.y, a.z, a.w};
        float bs[8] = {b0.x, b0.y, b0.z, b0.w, b1.x, b1.y, b1.z, b1.w};
#pragma unroll
        for (int i = 0; i < 4; ++i)
#pragma unroll
          for (int j = 0; j < 8; ++j) accO[i][j] += as[i] * bs[j];
      }
    }

    ++it;
    if (it == 13) { it = 0; ++rr; }
  }
#undef ISSUE

  // write partial P[rg][b][s][o]
  float* pp = P + ((size_t)rg * NB + b) * NS * NH;
#pragma unroll
  for (int i = 0; i < 4; ++i) {
    int srow = g1 * 4 + i;
    int o = o0 + g2 * 8;
    float* row = pp + (size_t)srow * NH + o;
    if (o + 7 < NH) {
      *(float4*)&row[0] = make_float4(accO[i][0], accO[i][1], accO[i][2], accO[i][3]);
      *(float4*)&row[4] = make_float4(accO[i][4], accO[i][5], accO[i][6], accO[i][7]);
    } else {
#pragma unroll
      for (int j = 0; j < 8; ++j)
        if (o + j < NH) row[j] = accO[i][j];
    }
  }
}

// ---- reduce partials + relu ----
__global__ void k_reduce(const float* __restrict__ P, float* __restrict__ y) {
  int idx = blockIdx.x * 256 + threadIdx.x;
  if (idx >= NB * NS * NH) return;
  float s = 0.f;
#pragma unroll
  for (int ch = 0; ch < RCH; ++ch) s += P[(size_t)ch * (NB * NS * NH) + idx];
  y[idx] = fmaxf(s, 0.f);
}

// ---- final: out[b,:] = concat(hg_mean, hc_mean) @ dW + db ----
__global__ void k_final(const float* __restrict__ hg, const float* __restrict__ rlen,
                        const float* __restrict__ hcm, const float* __restrict__ dW,
                        const float* __restrict__ db, float* __restrict__ out) {
  int b = blockIdx.x;
  __shared__ float hgm[NH];
  int tid = threadIdx.x;
  for (int h = tid; h < NH; h += 256) {
    float s = 0.f;
    for (int ss = 0; ss < NS; ++ss) s += hg[((size_t)(b * NS) + ss) * NH + h];
    hgm[h] = s / rlen[b];
  }
  __syncthreads();
  if (tid < 3) {
    float s = db[tid];
    for (int h = 0; h < NH; ++h) s += hgm[h] * dW[h * 3 + tid];
    for (int h = 0; h < NH; ++h) s += hcm[b * NH + h] * dW[(NH + h) * 3 + tid];
    out[b * 3 + tid] = s;
  }
}

extern "C" void kernel_launch(void* const* d_in, const int* in_sizes, int n_in,
                              void* d_out, int out_size, void* d_ws, size_t ws_size,
                              hipStream_t stream) {
  (void)in_sizes; (void)n_in; (void)out_size; (void)ws_size;
  const float* text   = (const float*)d_in[0];
  const int*   cmask  = (const int*)d_in[1];
  const int*   ptags  = (const int*)d_in[2];
  const float* adj    = (const float*)d_in[3];
  const float* pemb   = (const float*)d_in[4];
  const float* linW   = (const float*)d_in[5];
  const float* linb   = (const float*)d_in[6];
  const float* rgcnW  = (const float*)d_in[7];
  const float* scoreW = (const float*)d_in[8];
  const float* scoreB = (const float*)d_in[9];
  const float* denseW = (const float*)d_in[10];
  const float* denseB = (const float*)d_in[11];
  float* out = (float*)d_out;
  float* ws = (float*)d_ws;

  float* tsum = ws + OFF_TSUM;
  float* elen = ws + OFF_ELEN;
  float* rlen = ws + OFF_RLEN;
  float* hcm  = ws + OFF_HCM;
  float* tab  = ws + OFF_TAB;
  float* hgA  = ws + OFF_HGA;
  float* hgB  = ws + OFF_HGB;
  float* swt  = ws + OFF_SWT;
  float* ubuf = ws + OFF_U;
  float* spre = ws + OFF_SPRE;
  float* rden = ws + OFF_RDEN;
  float* cbuf = ws + OFF_C;
  float* Pbuf = ws + OFF_P;

  k_tsum<<<dim3(NB), dim3(256), 0, stream>>>(text, tsum);
  k_len<<<dim3(1), dim3(64), 0, stream>>>(cmask, ptags, elen, rlen);
  k_hcmean<<<dim3((NB * NH + 255) / 256), dim3(256), 0, stream>>>(tsum, linW, linb, elen, hcm);
  k_table<<<dim3((50 * NH + 255) / 256), dim3(256), 0, stream>>>(pemb, linW, linb, tab);
  k_gather<<<dim3((NB * NS * NH + 255) / 256), dim3(256), 0, stream>>>(ptags, tab, hgA);

  float* x = hgA;
  float* yb = hgB;
  for (int l = 0; l < 2; ++l) {
    const float* Wl = rgcnW + (size_t)l * NR * NH * NH;
    k_swt<<<dim3((NR * NH) / 4), dim3(256), 0, stream>>>(Wl, scoreW + l * NH, swt);
    k_u<<<dim3((NB * NR * NS) / 4), dim3(256), 0, stream>>>(x, swt, ubuf);
    k_scores<<<dim3((NB * NR * NS) / 4), dim3(256), 0, stream>>>(adj, ubuf, scoreB + l, spre, rden);
    k_softmax<<<dim3((NB * NS + 255) / 256), dim3(256), 0, stream>>>(spre, rden, cbuf);
    k_fused<<<dim3(NB * RCH * OCT), dim3(192), 0, stream>>>(adj, x, cbuf, Wl, Pbuf);
    k_reduce<<<dim3((NB * NS * NH + 255) / 256), dim3(256), 0, stream>>>(Pbuf, yb);
    float* tswap = x; x = yb; yb = tswap;
  }
  k_final<<<dim3(NB), dim3(256), 0, stream>>>(x, rlen, hcm, denseW, denseB, out);
}

// Round 9
// 2434.253 us; speedup vs baseline: 1.0636x; 1.0636x over previous
//
#include <hip/hip_runtime.h>

#define NB 32
#define NLEN 128
#define NS 96
#define NE 768
#define NH 300
#define NR 41
#define RCH 5     // r-chunks {9,8,8,8,8}; grid 800 = 8 XCD * 100, <= 4 blocks/CU capacity
#define OCT 5     // o-tiles of 64

// workspace offsets (in floats)
#define OFF_TSUM   0u
#define OFF_ELEN   24576u
#define OFF_RLEN   24608u
#define OFF_HCM    24640u
#define OFF_TAB    34240u
#define OFF_HGA    49240u
#define OFF_HGB    970840u
#define OFF_SWT    1892440u
#define OFF_U      1904740u
#define OFF_SPRE   2030692u
#define OFF_RDEN   2156644u
#define OFF_C      2282596u
#define OFF_P      2408548u   // [RCH][NB][NS][NH] f32 = 4,608,000 floats

// swizzle: spread 32-float groups by 4; quads/8-runs stay contiguous.
__device__ __forceinline__ int SW(int o) { return o + ((o >> 5) << 2); }

__device__ __forceinline__ float wave_reduce(float v) {
#pragma unroll
  for (int off = 32; off > 0; off >>= 1) v += __shfl_down(v, off);
  return v;
}

// ---- tsum[b,e] = sum_l text[b,l,e] ----
__global__ void k_tsum(const float* __restrict__ text, float* __restrict__ tsum) {
  int b = blockIdx.x;
  int tid = threadIdx.x;
  for (int e = tid; e < NE; e += 256) {
    const float* p = text + (size_t)b * NLEN * NE + e;
    float s = 0.f;
#pragma unroll 4
    for (int l = 0; l < NLEN; ++l) s += p[(size_t)l * NE];
    tsum[b * NE + e] = s;
  }
}

// ---- lengths ----
__global__ void k_len(const int* __restrict__ cm, const int* __restrict__ pt,
                      float* __restrict__ elen, float* __restrict__ rlen) {
  int b = threadIdx.x;
  if (b < NB) {
    int s1 = 0;
    for (int l = 0; l < NLEN; ++l) s1 += cm[b * NLEN + l];
    int s2 = 0;
    for (int s = 0; s < NS; ++s) s2 += (pt[b * NS + s] != 0) ? 1 : 0;
    elen[b] = (float)s1;
    rlen[b] = (float)s2;
  }
}

// ---- hc_mean[b,h] = (tsum[b]·linW[:,h] + L*linb[h]) / elen[b] ----
__global__ void k_hcmean(const float* __restrict__ tsum, const float* __restrict__ linW,
                         const float* __restrict__ linb, const float* __restrict__ elen,
                         float* __restrict__ hcm) {
  int idx = blockIdx.x * 256 + threadIdx.x;
  if (idx >= NB * NH) return;
  int b = idx / NH, h = idx - b * NH;
  const float* tp = tsum + b * NE;
  float s = 0.f;
  for (int e = 0; e < NE; ++e) s += tp[e] * linW[(size_t)e * NH + h];
  hcm[idx] = (s + (float)NLEN * linb[h]) / elen[b];
}

// ---- table[p,h] = pos_emb[p]·linW[:,h] + linb[h] ----
__global__ void k_table(const float* __restrict__ pemb, const float* __restrict__ linW,
                        const float* __restrict__ linb, float* __restrict__ tab) {
  int idx = blockIdx.x * 256 + threadIdx.x;
  if (idx >= 50 * NH) return;
  int p = idx / NH, h = idx - p * NH;
  const float* pp = pemb + (size_t)p * NE;
  float s = 0.f;
  for (int e = 0; e < NE; ++e) s += pp[e] * linW[(size_t)e * NH + h];
  tab[idx] = s + linb[h];
}

// ---- hg0[b,s,h] = table[pt[b,s],h] ----
__global__ void k_gather(const int* __restrict__ pt, const float* __restrict__ tab,
                         float* __restrict__ hg) {
  int idx = blockIdx.x * 256 + threadIdx.x;
  if (idx >= NB * NS * NH) return;
  int h = idx % NH;
  int bs = idx / NH;
  hg[idx] = tab[pt[bs] * NH + h];
}

// ---- swt[r,i] = sum_o W[r,i,o]*sw[o] ----
__global__ void k_swt(const float* __restrict__ Wl, const float* __restrict__ sw,
                      float* __restrict__ swt) {
  int gw = (blockIdx.x * blockDim.x + threadIdx.x) >> 6;
  int lane = threadIdx.x & 63;
  if (gw >= NR * NH) return;
  const float* wp = Wl + (size_t)gw * NH;
  float s = 0.f;
  for (int o = lane; o < NH; o += 64) s += wp[o] * sw[o];
  s = wave_reduce(s);
  if (lane == 0) swt[gw] = s;
}

// ---- u[b,r,t] = x[b,t,:]·swt[r,:] ----
__global__ void k_u(const float* __restrict__ x, const float* __restrict__ swt,
                    float* __restrict__ u) {
  int gw = (blockIdx.x * blockDim.x + threadIdx.x) >> 6;
  int lane = threadIdx.x & 63;
  if (gw >= NB * NR * NS) return;
  int t = gw % NS;
  int br = gw / NS;
  int r = br % NR;
  int b = br / NR;
  const float* xp = x + (size_t)(b * NS + t) * NH;
  const float* sp = swt + (size_t)r * NH;
  float s = 0.f;
  for (int i = lane; i < NH; i += 64) s += xp[i] * sp[i];
  s = wave_reduce(s);
  if (lane == 0) u[gw] = s;
}

// ---- denom + v + pre-softmax scores ----
__global__ void k_scores(const float* __restrict__ adj, const float* __restrict__ u,
                         const float* __restrict__ sb, float* __restrict__ spre,
                         float* __restrict__ rden) {
  int gw = (blockIdx.x * blockDim.x + threadIdx.x) >> 6;
  int lane = threadIdx.x & 63;
  if (gw >= NB * NR * NS) return;
  int s = gw % NS;
  int br = gw / NS;
  int r = br % NR;
  int b = br / NR;
  const float* ap = adj + (size_t)gw * NS;
  const float* up = u + (size_t)br * NS;
  float d = 0.f, v = 0.f;
  for (int t = lane; t < NS; t += 64) {
    float a = ap[t];
    d += a;
    v += a * up[t];
  }
  d = wave_reduce(d);
  v = wave_reduce(v);
  if (lane == 0) {
    float ds = (d == 0.f) ? 1.f : d;
    int o = (b * NS + s) * NR + r;
    spre[o] = v / ds + sb[0];
    rden[o] = 1.f / ds;
  }
}

// ---- softmax over r, fold 1/denom: c[b,r,s] ----
__global__ void k_softmax(const float* __restrict__ spre, const float* __restrict__ rden,
                          float* __restrict__ c) {
  int bs = blockIdx.x * 256 + threadIdx.x;
  if (bs >= NB * NS) return;
  int b = bs / NS, s = bs - b * NS;
  float vals[NR];
  float m = -1e30f;
#pragma unroll
  for (int r = 0; r < NR; ++r) {
    vals[r] = spre[(size_t)bs * NR + r];
    m = fmaxf(m, vals[r]);
  }
  float sum = 0.f;
#pragma unroll
  for (int r = 0; r < NR; ++r) {
    float e = expf(vals[r] - m);
    vals[r] = e;
    sum += e;
  }
  float inv = 1.f / sum;
#pragma unroll
  for (int r = 0; r < NR; ++r) {
    c[((size_t)(b * NR + r)) * NS + s] = vals[r] * inv * rden[(size_t)bs * NR + r];
  }
}

// ---- fused per-relation: Ht = x[b]@W_r[:,o-tile]; accO += (c⊙adjT)@Ht ----
// block = (b, rg, oc); 192 threads; micro-tile 4x8.
// Simple two-barrier stage/compute (R1 structure, ~120 VGPR) + LDS overlay:
//   sB (W tile, GEMM1 only) shares memory with sH (Ht, GEMM2 only)
//   -> 39936 B LDS -> 4 blocks/CU.
__global__ __launch_bounds__(192, 3)
void k_fused(const float* __restrict__ adj, const float* __restrict__ x,
             const float* __restrict__ cbuf, const float* __restrict__ Wl,
             float* __restrict__ P) {
  __shared__ __align__(16) float smem[9984];   // 39936 B
  float* sA = smem;            // 32*108 = 3456 floats: x-chunk / scaled-adjT, [k][SW(row)]
  float* sB = smem + 3456;     // 32*68  = 2176 floats: W-chunk (GEMM1 only)
  float* sH = smem + 3456;     // 96*68  = 6528 floats: Ht (GEMM2 only; overlays sB)

  const int tid = threadIdx.x;
  // XCD-chunked bijective swizzle: 800 = 8 * 100 exactly
  int w = ((blockIdx.x & 7) * 100) + (blockIdx.x >> 3);
  const int oc = w % 5; w /= 5;
  const int rg = w % 5;
  const int b = w / 5;
  const int o0 = oc * 64;
  const int r0 = (rg == 0) ? 0 : (9 + (rg - 1) * 8);
  const int nr = (rg == 0) ? 9 : 8;

  const int g1 = tid >> 3;        // row-group (t in G1, s in G2)
  const int g2 = tid & 7;         // col-group
  const int fa = SW(g1 * 4);
  const int fb = SW(g2 * 8);

  float accO[4][8];
#pragma unroll
  for (int i = 0; i < 4; ++i)
#pragma unroll
    for (int j = 0; j < 8; ++j) accO[i][j] = 0.f;

  const float* xb = x + (size_t)b * NS * NH;

  for (int rr = 0; rr < nr; ++rr) {
    const int r = r0 + rr;
    const float* wp = Wl + (size_t)r * NH * NH;
    const float* ap = adj + (size_t)(b * NR + r) * NS * NS;
    const float* cp = cbuf + (size_t)(b * NR + r) * NS;

    float acc1[4][8];
#pragma unroll
    for (int i = 0; i < 4; ++i)
#pragma unroll
      for (int j = 0; j < 8; ++j) acc1[i][j] = 0.f;

    // ---- GEMM1: Ht[t][o] = sum_k x[b][t][k] * W[r][k][o0+o], K=300 in 10 chunks
    for (int kc = 0; kc < 10; ++kc) {
      const int k0 = kc * 32;
      __syncthreads();  // prev compute done before restage
      // stage x: transposed write [kk][SW(t)]
#pragma unroll
      for (int p = 0; p < 4; ++p) {
        int idx = tid + p * 192;
        int kq = (idx & 7) * 4;
        int t = idx >> 3;
        int k = k0 + kq;
        float4 v = make_float4(0.f, 0.f, 0.f, 0.f);
        if (k + 3 < NH) v = *(const float4*)&xb[t * NH + k];
        int col = SW(t);
        sA[(kq + 0) * 108 + col] = v.x;
        sA[(kq + 1) * 108 + col] = v.y;
        sA[(kq + 2) * 108 + col] = v.z;
        sA[(kq + 3) * 108 + col] = v.w;
      }
      // stage W: [kk][SW(o)] direct float4
#pragma unroll
      for (int p = 0; p < 3; ++p) {
        int idx = tid + p * 192;
        if (idx < 512) {
          int oq = (idx & 15) * 4;
          int kk = idx >> 4;
          int k = k0 + kk;
          int o = o0 + oq;
          float4 v = make_float4(0.f, 0.f, 0.f, 0.f);
          if (k < NH) {
            const float* wrow = wp + (size_t)k * NH;
            v.x = (o + 0 < NH) ? wrow[o + 0] : 0.f;
            v.y = (o + 1 < NH) ? wrow[o + 1] : 0.f;
            v.z = (o + 2 < NH) ? wrow[o + 2] : 0.f;
            v.w = (o + 3 < NH) ? wrow[o + 3] : 0.f;
          }
          *(float4*)&sB[kk * 68 + SW(oq)] = v;
        }
      }
      __syncthreads();
#pragma unroll
      for (int kk = 0; kk < 32; ++kk) {
        float4 a = *(const float4*)&sA[kk * 108 + fa];
        float4 b0 = *(const float4*)&sB[kk * 68 + fb];
        float4 b1 = *(const float4*)&sB[kk * 68 + fb + 4];
        float as[4] = {a.x, a.y, a.z, a.w};
        float bs[8] = {b0.x, b0.y, b0.z, b0.w, b1.x, b1.y, b1.z, b1.w};
#pragma unroll
        for (int i = 0; i < 4; ++i)
#pragma unroll
          for (int j = 0; j < 8; ++j) acc1[i][j] += as[i] * bs[j];
      }
    }

    // ---- GEMM2: accO[s][o] += sum_t c[b,r,s]*adj[b,r,s,t] * Ht[t][o], K=96 in 3 chunks
    for (int tc = 0; tc < 3; ++tc) {
      const int t0 = tc * 32;
      __syncthreads();  // tc==0: all G1 reads of sB/sA done -> safe to overlay sH
      if (tc == 0) {
        // publish Ht into the sB/sH overlay (own cells)
#pragma unroll
        for (int i = 0; i < 4; ++i) {
          *(float4*)&sH[(g1 * 4 + i) * 68 + fb] =
              make_float4(acc1[i][0], acc1[i][1], acc1[i][2], acc1[i][3]);
          *(float4*)&sH[(g1 * 4 + i) * 68 + fb + 4] =
              make_float4(acc1[i][4], acc1[i][5], acc1[i][6], acc1[i][7]);
        }
      }
#pragma unroll
      for (int p = 0; p < 4; ++p) {
        int idx = tid + p * 192;
        int tq = (idx & 7) * 4;
        int s = idx >> 3;
        float4 v = *(const float4*)&ap[s * NS + t0 + tq];
        float cs = cp[s];
        int col = SW(s);
        sA[(tq + 0) * 108 + col] = v.x * cs;
        sA[(tq + 1) * 108 + col] = v.y * cs;
        sA[(tq + 2) * 108 + col] = v.z * cs;
        sA[(tq + 3) * 108 + col] = v.w * cs;
      }
      __syncthreads();
#pragma unroll
      for (int kk = 0; kk < 32; ++kk) {
        float4 a = *(const float4*)&sA[kk * 108 + fa];
        float4 b0 = *(const float4*)&sH[(t0 + kk) * 68 + fb];
        float4 b1 = *(const float4*)&sH[(t0 + kk) * 68 + fb + 4];
        float as[4] = {a.x, a.y, a.z, a.w};
        float bs[8] = {b0.x, b0.y, b0.z, b0.w, b1.x, b1.y, b1.z, b1.w};
#pragma unroll
        for (int i = 0; i < 4; ++i)
#pragma unroll
          for (int j = 0; j < 8; ++j) accO[i][j] += as[i] * bs[j];
      }
    }
  }

  // write partial P[rg][b][s][o]
  float* pp = P + ((size_t)rg * NB + b) * NS * NH;
#pragma unroll
  for (int i = 0; i < 4; ++i) {
    int srow = g1 * 4 + i;
    int o = o0 + g2 * 8;
    float* row = pp + (size_t)srow * NH + o;
    if (o + 7 < NH) {
      *(float4*)&row[0] = make_float4(accO[i][0], accO[i][1], accO[i][2], accO[i][3]);
      *(float4*)&row[4] = make_float4(accO[i][4], accO[i][5], accO[i][6], accO[i][7]);
    } else {
#pragma unroll
      for (int j = 0; j < 8; ++j)
        if (o + j < NH) row[j] = accO[i][j];
    }
  }
}

// ---- reduce partials + relu ----
__global__ void k_reduce(const float* __restrict__ P, float* __restrict__ y) {
  int idx = blockIdx.x * 256 + threadIdx.x;
  if (idx >= NB * NS * NH) return;
  float s = 0.f;
#pragma unroll
  for (int ch = 0; ch < RCH; ++ch) s += P[(size_t)ch * (NB * NS * NH) + idx];
  y[idx] = fmaxf(s, 0.f);
}

// ---- final: out[b,:] = concat(hg_mean, hc_mean) @ dW + db ----
__global__ void k_final(const float* __restrict__ hg, const float* __restrict__ rlen,
                        const float* __restrict__ hcm, const float* __restrict__ dW,
                        const float* __restrict__ db, float* __restrict__ out) {
  int b = blockIdx.x;
  __shared__ float hgm[NH];
  int tid = threadIdx.x;
  for (int h = tid; h < NH; h += 256) {
    float s = 0.f;
    for (int ss = 0; ss < NS; ++ss) s += hg[((size_t)(b * NS) + ss) * NH + h];
    hgm[h] = s / rlen[b];
  }
  __syncthreads();
  if (tid < 3) {
    float s = db[tid];
    for (int h = 0; h < NH; ++h) s += hgm[h] * dW[h * 3 + tid];
    for (int h = 0; h < NH; ++h) s += hcm[b * NH + h] * dW[(NH + h) * 3 + tid];
    out[b * 3 + tid] = s;
  }
}

extern "C" void kernel_launch(void* const* d_in, const int* in_sizes, int n_in,
                              void* d_out, int out_size, void* d_ws, size_t ws_size,
                              hipStream_t stream) {
  (void)in_sizes; (void)n_in; (void)out_size; (void)ws_size;
  const float* text   = (const float*)d_in[0];
  const int*   cmask  = (const int*)d_in[1];
  const int*   ptags  = (const int*)d_in[2];
  const float* adj    = (const float*)d_in[3];
  const float* pemb   = (const float*)d_in[4];
  const float* linW   = (const float*)d_in[5];
  const float* linb   = (const float*)d_in[6];
  const float* rgcnW  = (const float*)d_in[7];
  const float* scoreW = (const float*)d_in[8];
  const float* scoreB = (const float*)d_in[9];
  const float* denseW = (const float*)d_in[10];
  const float* denseB = (const float*)d_in[11];
  float* out = (float*)d_out;
  float* ws = (float*)d_ws;

  float* tsum = ws + OFF_TSUM;
  float* elen = ws + OFF_ELEN;
  float* rlen = ws + OFF_RLEN;
  float* hcm  = ws + OFF_HCM;
  float* tab  = ws + OFF_TAB;
  float* hgA  = ws + OFF_HGA;
  float* hgB  = ws + OFF_HGB;
  float* swt  = ws + OFF_SWT;
  float* ubuf = ws + OFF_U;
  float* spre = ws + OFF_SPRE;
  float* rden = ws + OFF_RDEN;
  float* cbuf = ws + OFF_C;
  float* Pbuf = ws + OFF_P;

  k_tsum<<<dim3(NB), dim3(256), 0, stream>>>(text, tsum);
  k_len<<<dim3(1), dim3(64), 0, stream>>>(cmask, ptags, elen, rlen);
  k_hcmean<<<dim3((NB * NH + 255) / 256), dim3(256), 0, stream>>>(tsum, linW, linb, elen, hcm);
  k_table<<<dim3((50 * NH + 255) / 256), dim3(256), 0, stream>>>(pemb, linW, linb, tab);
  k_gather<<<dim3((NB * NS * NH + 255) / 256), dim3(256), 0, stream>>>(ptags, tab, hgA);

  float* x = hgA;
  float* yb = hgB;
  for (int l = 0; l < 2; ++l) {
    const float* Wl = rgcnW + (size_t)l * NR * NH * NH;
    k_swt<<<dim3((NR * NH) / 4), dim3(256), 0, stream>>>(Wl, scoreW + l * NH, swt);
    k_u<<<dim3((NB * NR * NS) / 4), dim3(256), 0, stream>>>(x, swt, ubuf);
    k_scores<<<dim3((NB * NR * NS) / 4), dim3(256), 0, stream>>>(adj, ubuf, scoreB + l, spre, rden);
    k_softmax<<<dim3((NB * NS + 255) / 256), dim3(256), 0, stream>>>(spre, rden, cbuf);
    k_fused<<<dim3(NB * RCH * OCT), dim3(192), 0, stream>>>(adj, x, cbuf, Wl, Pbuf);
    k_reduce<<<dim3((NB * NS * NH + 255) / 256), dim3(256), 0, stream>>>(Pbuf, yb);
    float* tswap = x; x = yb; yb = tswap;
  }
  k_final<<<dim3(NB), dim3(256), 0, stream>>>(x, rlen, hcm, denseW, denseB, out);
}